// Round 2
// baseline (1647.870 us; speedup 1.0000x reference)
//
#include <hip/hip_runtime.h>
#include <cmath>

// All harness inputs/outputs are float32 (per reference dtypes).
// Internally we cast GEMM operands to bf16 (u16 bits) for MFMA.
typedef __bf16 bf16x8 __attribute__((ext_vector_type(8)));
typedef float f32x4 __attribute__((ext_vector_type(4)));

__device__ __forceinline__ float b2f(unsigned short u) {
  union { unsigned int i; float f; } v;
  v.i = ((unsigned int)u) << 16;
  return v.f;
}
__device__ __forceinline__ unsigned short f2b(float f) {
  union { float f; unsigned int i; } v;
  v.f = f;
  unsigned int i = v.i;
  return (unsigned short)((i + 0x7FFFu + ((i >> 16) & 1u)) >> 16);  // RNE
}

// ---------------------------------------------------------------------------
// Cast f32 -> bf16, 4 elements/thread.  n divisible by 1024.
// ---------------------------------------------------------------------------
__global__ __launch_bounds__(256) void k_cast(const float* __restrict__ src,
                                              unsigned short* __restrict__ dst,
                                              int n4) {
  int gid = blockIdx.x * 256 + threadIdx.x;
  if (gid >= n4) return;
  float4 v = *(const float4*)(src + (long)gid * 4);
  uint2 r;
  r.x = (unsigned int)f2b(v.x) | ((unsigned int)f2b(v.y) << 16);
  r.y = (unsigned int)f2b(v.z) | ((unsigned int)f2b(v.w) << 16);
  *(uint2*)(dst + (long)gid * 4) = r;
}

// ---------------------------------------------------------------------------
// pool (mean over 16) + gelu(pooled).  single: (16384,768) f32.
// Outputs bf16.  grid = 1024*192/256 = 768 blocks.
// ---------------------------------------------------------------------------
__global__ __launch_bounds__(256) void k_pool(const float* __restrict__ single,
                                              unsigned short* __restrict__ pooled,
                                              unsigned short* __restrict__ gpool) {
  int gid = blockIdx.x * 256 + threadIdx.x;
  int n = gid / 192;
  int dq = (gid - n * 192) * 4;
  const float* src = single + (long)n * (16 * 768) + dq;
  float s0 = 0.f, s1 = 0.f, s2 = 0.f, s3 = 0.f;
#pragma unroll
  for (int t = 0; t < 16; t++) {
    float4 u = *(const float4*)(src + t * 768);
    s0 += u.x; s1 += u.y; s2 += u.z; s3 += u.w;
  }
  float p0 = s0 * 0.0625f, p1 = s1 * 0.0625f, p2 = s2 * 0.0625f, p3 = s3 * 0.0625f;
  const float inv_sqrt2 = 0.70710678118654752f;
  float g0 = 0.5f * p0 * (1.f + erff(p0 * inv_sqrt2));
  float g1 = 0.5f * p1 * (1.f + erff(p1 * inv_sqrt2));
  float g2 = 0.5f * p2 * (1.f + erff(p2 * inv_sqrt2));
  float g3 = 0.5f * p3 * (1.f + erff(p3 * inv_sqrt2));
  long o = (long)n * 768 + dq;
  uint2 rp, rg;
  rp.x = (unsigned int)f2b(p0) | ((unsigned int)f2b(p1) << 16);
  rp.y = (unsigned int)f2b(p2) | ((unsigned int)f2b(p3) << 16);
  rg.x = (unsigned int)f2b(g0) | ((unsigned int)f2b(g1) << 16);
  rg.y = (unsigned int)f2b(g2) | ((unsigned int)f2b(g3) << 16);
  *(uint2*)(pooled + o) = rp;
  *(uint2*)(gpool + o) = rg;
}

// ---------------------------------------------------------------------------
// Generic MFMA GEMM: C = A(M x K) . B(N x K)^T, bf16 inputs, templated
// epilogue receives (m, n, batch, value_f32).  64x64 tile / block, 4 waves,
// 16x16x32 MFMA.  M,N multiples of 64; K multiple of 32.
// ---------------------------------------------------------------------------
template <class Epi>
__global__ __launch_bounds__(256) void gemm_bt(const unsigned short* __restrict__ A,
                                               const unsigned short* __restrict__ B,
                                               int K, long sA, long sB, Epi epi) {
  __shared__ __align__(16) unsigned short As[64][40];  // pad 40: conflict-free b128
  __shared__ __align__(16) unsigned short Bs[64][40];
  const int tid = threadIdx.x;
  const int lane = tid & 63;
  const int wave = tid >> 6;
  const int wm = wave >> 1;
  const int wn = wave & 1;
  const int z = blockIdx.z;
  const unsigned short* Ab = A + (long)z * sA;
  const unsigned short* Bb = B + (long)z * sB;
  const int m0 = blockIdx.x * 64;
  const int n0 = blockIdx.y * 64;
  const int lrow = tid >> 2;          // 0..63
  const int lcol = (tid & 3) * 8;     // 0,8,16,24
  const int frow = lane & 15;
  const int fk = (lane >> 4) * 8;

  f32x4 zero = {0.f, 0.f, 0.f, 0.f};
  f32x4 acc00 = zero, acc01 = zero, acc10 = zero, acc11 = zero;

  for (int k0 = 0; k0 < K; k0 += 32) {
    *(uint4*)(&As[lrow][lcol]) = *(const uint4*)(Ab + (long)(m0 + lrow) * K + k0 + lcol);
    *(uint4*)(&Bs[lrow][lcol]) = *(const uint4*)(Bb + (long)(n0 + lrow) * K + k0 + lcol);
    __syncthreads();
    bf16x8 a0 = *(const bf16x8*)(&As[wm * 32 + frow][fk]);
    bf16x8 a1 = *(const bf16x8*)(&As[wm * 32 + 16 + frow][fk]);
    bf16x8 b0 = *(const bf16x8*)(&Bs[wn * 32 + frow][fk]);
    bf16x8 b1 = *(const bf16x8*)(&Bs[wn * 32 + 16 + frow][fk]);
    acc00 = __builtin_amdgcn_mfma_f32_16x16x32_bf16(a0, b0, acc00, 0, 0, 0);
    acc01 = __builtin_amdgcn_mfma_f32_16x16x32_bf16(a0, b1, acc01, 0, 0, 0);
    acc10 = __builtin_amdgcn_mfma_f32_16x16x32_bf16(a1, b0, acc10, 0, 0, 0);
    acc11 = __builtin_amdgcn_mfma_f32_16x16x32_bf16(a1, b1, acc11, 0, 0, 0);
    __syncthreads();
  }
  // C/D layout: col = lane&15, row = (lane>>4)*4 + reg  [m89/m91 verified]
  const int em = m0 + wm * 32 + (lane >> 4) * 4;
  const int en = n0 + wn * 32 + (lane & 15);
#pragma unroll
  for (int r = 0; r < 4; r++) {
    epi(em + r,      en,      z, acc00[r]);
    epi(em + r,      en + 16, z, acc01[r]);
    epi(em + 16 + r, en,      z, acc10[r]);
    epi(em + 16 + r, en + 16, z, acc11[r]);
  }
}

// --- epilogues --------------------------------------------------------------
// qk GEMM: n in [0,8192).  n<4096 -> q head h=n>>7, d=n&127; else k.
// Also store biased copies (q+q_bias, k+k_bias) for the rel GEMMs.
// Layouts: q/k/qb/kb as [h][i][d] bf16.  bias is f32 flat [2][32][128]==[n].
struct EpiQK {
  unsigned short* q; unsigned short* k; unsigned short* qb; unsigned short* kb;
  const float* bias;
  __device__ void operator()(int m, int n, int z, float v) const {
    int co = n & 4095;
    int h = co >> 7, d = co & 127;
    long o = ((long)h * 1024 + m) * 128 + d;
    float bv = bias[n];
    if (n < 4096) { q[o] = f2b(v); qb[o] = f2b(v + bv); }
    else          { k[o] = f2b(v); kb[o] = f2b(v + bv); }
  }
};
// rel_enc GEMM: store [hs][p][d] bf16, + b_rel (f32).
struct EpiRel {
  unsigned short* rel; const float* brel;
  __device__ void operator()(int m, int n, int z, float v) const {
    int h = n >> 7, d = n & 127;
    rel[((long)h * 2048 + m) * 128 + d] = f2b(v + brel[n]);
  }
};
// outer GEMM: n<128 -> outer_q (f32), else outer_k.
struct EpiOuter {
  float* oq; float* ok;
  __device__ void operator()(int m, int n, int z, float v) const {
    if (n < 128) oq[(long)m * 128 + n] = v;
    else         ok[(long)m * 128 + (n - 128)] = v;
  }
};
// sim: batch z = head.  S layout [i][h][j] bf16, contiguous in j.
struct EpiSim {
  unsigned short* S;
  __device__ void operator()(int m, int n, int z, float v) const {
    S[((long)m * 32 + z) * 1024 + n] = f2b(v);
  }
};
// rel_q scatter: batch z = hs, col n -> ps = 544+n.  t = 33*ps+hs+1-18432;
// valid t in [0,32768): j=t>>5, h=t&31;  S[i=m][h][j] += 0.5*v.
struct EpiRQ {
  unsigned short* S;
  __device__ void operator()(int m, int n, int z, float v) const {
    int t = 33 * (544 + n) + z + 1 - 18432;
    if (t >= 0 && t < 32768) {
      int j = t >> 5, h = t & 31;
      long o = ((long)m * 32 + h) * 1024 + j;
      S[o] = f2b(b2f(S[o]) + 0.5f * v);
    }
  }
};
// rel_k scatter: rows m = j; (ps,hs) -> (i,h).  S[i][h][j=m] += 0.5*v.
struct EpiRK {
  unsigned short* S;
  __device__ void operator()(int m, int n, int z, float v) const {
    int t = 33 * (544 + n) + z + 1 - 18432;
    if (t >= 0 && t < 32768) {
      int i = t >> 5, h = t & 31;
      long o = ((long)i * 32 + h) * 1024 + m;
      S[o] = f2b(b2f(S[o]) + 0.5f * v);
    }
  }
};

// ---------------------------------------------------------------------------
// Final: out[i][j][c] = sum_h S[i][h][j]*w_pair[c][h] + oq[i][c] + ok[j][c]
//        + b_pair[c].   One K=32 MFMA per 16j x 16c tile (h is the K dim).
// Block: (i, j-tile of 64), 4 waves x 16 j each, loop 8 c-tiles.  out is f32.
// ---------------------------------------------------------------------------
__global__ __launch_bounds__(256) void k_final2(const unsigned short* __restrict__ S,
                                                const float* __restrict__ oq,
                                                const float* __restrict__ ok,
                                                const float* __restrict__ wp,
                                                const float* __restrict__ bp,
                                                float* __restrict__ out) {
  __shared__ __align__(16) unsigned short sl[32][72];  // [h][j]
  const int i = blockIdx.y;
  const int j0 = blockIdx.x * 64;
  const int t = threadIdx.x;
  {
    int h = t >> 3;
    int jj = (t & 7) * 8;
    uint4 raw = *(const uint4*)(S + ((long)i * 32 + h) * 1024 + j0 + jj);
    *(uint4*)(&sl[h][jj]) = raw;
  }
  __syncthreads();
  const int lane = t & 63;
  const int wv = t >> 6;
  const int jbase = wv * 16;
  const int r16 = lane & 15;
  const int kq = lane >> 4;
  union { unsigned short u[8]; bf16x8 v; } af;
#pragma unroll
  for (int s = 0; s < 8; s++) af.u[s] = sl[kq * 8 + s][jbase + r16];  // A[j][h]
#pragma unroll
  for (int ct = 0; ct < 8; ct++) {
    const int c0 = ct * 16;
    union { unsigned short u[8]; bf16x8 v; } bfr;
#pragma unroll
    for (int s = 0; s < 8; s++) bfr.u[s] = f2b(wp[(c0 + r16) * 32 + kq * 8 + s]);  // B[c][h]
    f32x4 acc = {0.f, 0.f, 0.f, 0.f};
    acc = __builtin_amdgcn_mfma_f32_16x16x32_bf16(af.v, bfr.v, acc, 0, 0, 0);
    const int cD = c0 + r16;
    const float addc = oq[i * 128 + cD] + bp[cD];
#pragma unroll
    for (int r = 0; r < 4; r++) {
      const int j = j0 + jbase + kq * 4 + r;
      out[(long)i * 131072 + j * 128 + cD] = acc[r] + addc + ok[j * 128 + cD];
    }
  }
}

// ---------------------------------------------------------------------------
extern "C" void kernel_launch(void* const* d_in, const int* in_sizes, int n_in,
                              void* d_out, int out_size, void* d_ws, size_t ws_size,
                              hipStream_t stream) {
  (void)in_sizes; (void)n_in; (void)out_size; (void)ws_size;
  const float* single  = (const float*)d_in[0];
  const float* relfeat = (const float*)d_in[1];
  const float* w_qk    = (const float*)d_in[2];
  const float* w_outer = (const float*)d_in[3];
  const float* w_pair  = (const float*)d_in[4];
  const float* b_pair  = (const float*)d_in[5];
  const float* w_rel   = (const float*)d_in[6];
  const float* b_rel   = (const float*)d_in[7];
  const float* qk_bias = (const float*)d_in[8];
  float* out = (float*)d_out;
  char* ws = (char*)d_ws;

  // workspace layout (bytes); total ~137.4 MiB
  unsigned short* pooled  = (unsigned short*)(ws + 0);          // 1024x768 bf16
  unsigned short* gpool   = (unsigned short*)(ws + 1572864);    // 1024x768 bf16
  unsigned short* q       = (unsigned short*)(ws + 3145728);    // [32][1024][128]
  unsigned short* k       = (unsigned short*)(ws + 11534336);
  unsigned short* qb      = (unsigned short*)(ws + 19922944);
  unsigned short* kb      = (unsigned short*)(ws + 28311552);
  unsigned short* rel     = (unsigned short*)(ws + 36700160);   // [32][2048][128]
  float*          oq      = (float*)(ws + 53477376);            // 1024x128 f32
  float*          okf     = (float*)(ws + 54001664);            // 1024x128 f32
  unsigned short* S       = (unsigned short*)(ws + 54525952);   // [1024][32][1024]
  unsigned short* wqk_b   = (unsigned short*)(ws + 121634816);  // 8192x768 bf16
  unsigned short* wrel_b  = (unsigned short*)(ws + 134217728);  // 4096x768 bf16
  unsigned short* rfeat_b = (unsigned short*)(ws + 140509184);  // 2048x768 bf16
  unsigned short* wout_b  = (unsigned short*)(ws + 143654912);  // 256x768 bf16

  // f32 -> bf16 casts for GEMM operands
  k_cast<<<6144, 256, 0, stream>>>(w_qk,    wqk_b,   1572864);
  k_cast<<<3072, 256, 0, stream>>>(w_rel,   wrel_b,   786432);
  k_cast<<<1536, 256, 0, stream>>>(relfeat, rfeat_b,  393216);
  k_cast<<< 192, 256, 0, stream>>>(w_outer, wout_b,    49152);

  k_pool<<<768, 256, 0, stream>>>(single, pooled, gpool);
  // qk = pooled @ w_qk^T   (M=1024, N=8192, K=768)
  gemm_bt<<<dim3(16, 128, 1), 256, 0, stream>>>(pooled, wqk_b, 768, 0L, 0L,
                                                EpiQK{q, k, qb, kb, qk_bias});
  // rel_enc = rel_pos_feats @ w_rel^T + b_rel   (M=2048, N=4096, K=768)
  gemm_bt<<<dim3(32, 64, 1), 256, 0, stream>>>(rfeat_b, wrel_b, 768, 0L, 0L,
                                               EpiRel{rel, b_rel});
  // outer = gelu(pooled) @ w_outer^T   (M=1024, N=256, K=768)
  gemm_bt<<<dim3(16, 4, 1), 256, 0, stream>>>(gpool, wout_b, 768, 0L, 0L,
                                              EpiOuter{oq, okf});
  // sim: per-head q.k^T   (32 batches, M=N=1024, K=128)
  gemm_bt<<<dim3(16, 16, 32), 256, 0, stream>>>(q, k, 128, 131072L, 131072L,
                                                EpiSim{S});
  // rel_q: per-hs (q+q_bias).rel_enc^T, ps in [544,1568), scatter += 0.5
  gemm_bt<<<dim3(16, 16, 32), 256, 0, stream>>>(qb, rel + 69632, 128, 131072L, 262144L,
                                                EpiRQ{S});
  // rel_k: same, rows = j, scatter += 0.5
  gemm_bt<<<dim3(16, 16, 32), 256, 0, stream>>>(kb, rel + 69632, 128, 131072L, 262144L,
                                                EpiRK{S});
  // final: pairwise + outer_sum -> out (f32)
  k_final2<<<dim3(16, 1024, 1), 256, 0, stream>>>(S, oq, okf, w_pair, b_pair, out);
}